// Round 2
// baseline (112.752 us; speedup 1.0000x reference)
//
#include <hip/hip_runtime.h>

#define PL 128
#define STRIDE 64
#define WSZ 16

// One fused kernel:
//  A) patches[p,t,{0,1}] gather (grid-stride, float4 = 2 t's per store)
//  B) per-thread adj fragment (64 elems) computed into 16 float4 registers
//     -- each 64KB adj tile is written as dst[k*256+tid], so with blockDim=256
//        a given thread always stores the SAME 16 float4 values for every patch
//  C) store-only broadcast loop: 16 global_store_dwordx4 per patch, no loads
__global__ __launch_bounds__(256) void fused_kernel(
    const float* __restrict__ I, const float* __restrict__ Q,
    const float* __restrict__ ew, float* __restrict__ out, int P)
{
    const int tid  = threadIdx.x;
    const int bid  = blockIdx.x;
    const int nblk = gridDim.x;

    // ---- Part A: patches [P,128,2] ----
    {
        float4* pout = reinterpret_cast<float4*>(out);
        const int total = P * (PL / 2);          // one float4 covers t, t+1
        for (int idx = bid * 256 + tid; idx < total; idx += nblk * 256) {
            int p = idx >> 6;                    // idx / 64
            int t = (idx & 63) * 2;
            int src = p * STRIDE + t;
            pout[idx] = make_float4(I[src], Q[src], I[src + 1], Q[src + 1]);
        }
    }

    // ---- Part B: this thread's 64 adj elements -> 16 float4 registers ----
    // element index = k*1024 + tid*4 + c  ->  i = k*8 + (tid>>5), j = (tid&31)*4 + c
    float4 v[16];
#pragma unroll
    for (int k = 0; k < 16; ++k) {
        const int i  = k * 8 + (tid >> 5);
        const int j0 = (tid & 31) * 4;
        float4 r = make_float4(0.f, 0.f, 0.f, 0.f);
        float* rp = &r.x;
#pragma unroll
        for (int c = 0; c < 4; ++c) {
            int j = j0 + c;
            int d = i - j; if (d < 0) d = -d;
            if (d > 0 && d <= WSZ) {
                rp[c] = 1.0f / (1.0f + __expf(-ew[i * PL + j]));
            }
        }
        v[k] = r;
    }

    // ---- Part C: store-only broadcast of adj to [P,128,128] ----
    float4* aout = reinterpret_cast<float4*>(out + (size_t)P * PL * 2);
    for (int p = bid; p < P; p += nblk) {
        float4* dst = aout + (size_t)p * (PL * PL / 4);
#pragma unroll
        for (int k = 0; k < 16; ++k) {
            dst[k * 256 + tid] = v[k];
        }
    }
}

extern "C" void kernel_launch(void* const* d_in, const int* in_sizes, int n_in,
                              void* d_out, int out_size, void* d_ws, size_t ws_size,
                              hipStream_t stream) {
    const float* I  = (const float*)d_in[0];
    const float* Q  = (const float*)d_in[1];
    const float* ew = (const float*)d_in[2];
    float* out = (float*)d_out;

    const int n = in_sizes[0];
    const int P = (n - PL) / STRIDE + 1;   // 7811 for L=500000

    const int nblk = (P + 3) / 4;          // ~4 patches per block, near-perfect balance
    fused_kernel<<<nblk, 256, 0, stream>>>(I, Q, ew, out, P);
}

// Round 4
// 107.266 us; speedup vs baseline: 1.0511x; 1.0511x over previous
//
#include <hip/hip_runtime.h>

#define PL 128
#define STRIDE 64
#define WSZ 16

typedef float f32x4 __attribute__((ext_vector_type(4)));

// One fused kernel:
//  A) patches[p,t,{0,1}] gather (grid-stride, f32x4 = 2 t's per store)
//  B) per-thread adj fragment (64 elems) computed into 16 f32x4 registers
//     -- each 64KB adj tile is written as dst[k*256+tid], so with blockDim=256
//        a given thread always stores the SAME 16 f32x4 values for every patch
//  C) store-only broadcast: block b owns contiguous patches [4b, 4b+4)
//     (256 KB contiguous per block for DRAM page locality), nontemporal
//     stores to bypass L2 write-allocate on the 512 MB stream.
__global__ __launch_bounds__(256) void fused_kernel(
    const float* __restrict__ I, const float* __restrict__ Q,
    const float* __restrict__ ew, float* __restrict__ out, int P)
{
    const int tid  = threadIdx.x;
    const int bid  = blockIdx.x;
    const int nblk = gridDim.x;

    // ---- Part A: patches [P,128,2] ----
    {
        f32x4* pout = reinterpret_cast<f32x4*>(out);
        const int total = P * (PL / 2);          // one f32x4 covers t, t+1
        for (int idx = bid * 256 + tid; idx < total; idx += nblk * 256) {
            int p = idx >> 6;                    // idx / 64
            int t = (idx & 63) * 2;
            int src = p * STRIDE + t;
            f32x4 val = {I[src], Q[src], I[src + 1], Q[src + 1]};
            __builtin_nontemporal_store(val, &pout[idx]);
        }
    }

    // ---- Part B: this thread's 64 adj elements -> 16 f32x4 registers ----
    // element index = k*1024 + tid*4 + c  ->  i = k*8 + (tid>>5), j = (tid&31)*4 + c
    f32x4 v[16];
#pragma unroll
    for (int k = 0; k < 16; ++k) {
        const int i  = k * 8 + (tid >> 5);
        const int j0 = (tid & 31) * 4;
        f32x4 r = {0.f, 0.f, 0.f, 0.f};
#pragma unroll
        for (int c = 0; c < 4; ++c) {
            int j = j0 + c;
            int d = i - j; if (d < 0) d = -d;
            if (d > 0 && d <= WSZ) {
                r[c] = 1.0f / (1.0f + __expf(-ew[i * PL + j]));
            }
        }
        v[k] = r;
    }

    // ---- Part C: store-only broadcast of adj to [P,128,128] ----
    f32x4* aout = reinterpret_cast<f32x4*>(out + (size_t)P * PL * 2);
    int p0 = bid * 4;
    int p1 = p0 + 4; if (p1 > P) p1 = P;
    for (int p = p0; p < p1; ++p) {
        f32x4* dst = aout + (size_t)p * (PL * PL / 4);
#pragma unroll
        for (int k = 0; k < 16; ++k) {
            __builtin_nontemporal_store(v[k], &dst[k * 256 + tid]);
        }
    }
}

extern "C" void kernel_launch(void* const* d_in, const int* in_sizes, int n_in,
                              void* d_out, int out_size, void* d_ws, size_t ws_size,
                              hipStream_t stream) {
    const float* I  = (const float*)d_in[0];
    const float* Q  = (const float*)d_in[1];
    const float* ew = (const float*)d_in[2];
    float* out = (float*)d_out;

    const int n = in_sizes[0];
    const int P = (n - PL) / STRIDE + 1;   // 7811 for L=500000

    const int nblk = (P + 3) / 4;          // block b -> patches [4b, 4b+4)
    fused_kernel<<<nblk, 256, 0, stream>>>(I, Q, ew, out, P);
}